// Round 3
// baseline (74.602 us; speedup 1.0000x reference)
//
#include <hip/hip_runtime.h>

typedef __attribute__((ext_vector_type(8)))  short short8;
typedef __attribute__((ext_vector_type(16))) float f32x16;
typedef unsigned int uint;
typedef unsigned long long ull;

#define SEQ    2048
#define XPITCH 20                  // u32 per x row (16 data + 4 pad); 5 coprime 8 -> conflict-free b128
#define XSZ    (64 * XPITCH)       // 1280 u32: x blocks 0..63 (no zero rows)
#define KSZ    1040                // u32: krev pairs, elements 0..2079 (tail zeros)
#define WSZ    (XSZ + KSZ)         // 2320 u32 = 9.28 KB per row
#define LDSU   (4 * WSZ + 16)      // + shared broadcast zero row

__device__ inline uint pack_bf16_2(float lo, float hi) {
    uint ul = __float_as_uint(lo);
    uint uh = __float_as_uint(hi);
    ul = (ul + 0x7fffu + ((ul >> 16) & 1u)) >> 16;   // RNE
    uh = (uh + 0x7fffu + ((uh >> 16) & 1u)) >> 16;
    return (ul & 0xffffu) | (uh << 16);
}

#define MFMA(A, B, C) __builtin_amdgcn_mfma_f32_32x32x16_bf16( \
    __builtin_bit_cast(short8, A), __builtin_bit_cast(short8, B), C, 0, 0, 0)

// funnel: ({hi,lo} >> sh)[31:0]; sh in {0,16}, lane-constant -> v_alignbit
__device__ inline uint fnl(uint h, uint l, uint sh) {
    return (uint)((((ull)h << 32) | l) >> sh);
}

// build B-frag (4 u32 = 8 bf16) from 6-u32 aligned window, lane-constant (c2, sh)
#define SEL4(W0, W1, W2, W3, W4, W5, OUT) {                          \
    uint t0 = c2 ? (W1) : (W0), t1 = c2 ? (W2) : (W1),               \
         t2 = c2 ? (W3) : (W2), t3 = c2 ? (W4) : (W3),               \
         t4 = c2 ? (W5) : (W4);                                      \
    OUT.x = fnl(t1, t0, sh); OUT.y = fnl(t2, t1, sh);                \
    OUT.z = fnl(t3, t2, sh); OUT.w = fnl(t4, t3, sh); }

// One wave per (b,d) row, 4 rows/block, 4 blocks/CU (37.2 KB LDS).
// Y(64x32) = sum_r shift_r(X) * T_r^T via 32x32x16 bf16 MFMA.
__global__ __launch_bounds__(256, 4)
void hyena_mfma(const float* __restrict__ x, const float* __restrict__ kern,
                const float* __restrict__ bias, float* __restrict__ out)
{
    __shared__ __align__(16) uint lds[LDSU];
    char* ldsb = (char*)lds;

    const int tid = threadIdx.x;
    const int wid = tid >> 6;
    const int l   = tid & 63;
    const int n   = l & 31;        // MFMA row (A) / col (B/D)
    const int hi  = l >> 5;        // k-group half
    const int row = blockIdx.x * 4 + wid;
    const size_t rb = (size_t)row * SEQ;

    uint* xw = lds + wid * WSZ;    // [64][20] u32 bf16 x blocks
    uint* kw = xw + XSZ;           // krev pairs: kw[w] = (krev[2w], krev[2w+1])

    // ---- stage x row as bf16 ----
    #pragma unroll
    for (int it = 0; it < 16; ++it) {
        const int e = it * 128 + 2 * l;
        float2 v = *(const float2*)&x[rb + e];
        xw[(e >> 5) * XPITCH + ((e & 31) >> 1)] = pack_bf16_2(v.x, v.y);
    }
    // ---- stage krev: krev[j] = k[2047-j], zero for j >= 2048 ----
    #pragma unroll
    for (int it = 0; it < 16; ++it) {
        const int j = it * 128 + 2 * l;
        float2 v = *(const float2*)&kern[rb + (2046 - j)];   // (k[2046-j], k[2047-j])
        kw[j >> 1] = pack_bf16_2(v.y, v.x);                  // (krev[j], krev[j+1])
    }
    if (l < 16) kw[1024 + l] = 0u;                           // krev tail zeros
    if (tid < 16) lds[4 * WSZ + tid] = 0u;                   // shared zero row
    __syncthreads();

    // ---- per-lane constants ----
    // B-frag(r,s) elements: krev[start + v], start = 2047 - n + 16s + 8hi - 32r
    const int st00 = 2047 - n + 8 * hi;         // start at r=0,s=0
    const bool c2  = (st00 & 2) != 0;           // u32-select bit (lane-constant)
    const uint sh  = (uint)(st00 & 1) << 4;     // bf16 funnel shift (lane-constant)
    // byte addr of aligned window base, rebased by -2048 so all 4 windows
    // have non-negative constant offsets: b10@0, b11@32, b00@2048, b01@2080
    int vk  = (wid * WSZ + XSZ) * 4 + ((st00 & ~3) << 1) - 2048;
    int va2 = wid * WSZ * 4 + (n + 32) * 80 + 16 * hi;   // A row (n-r+32), always valid
    const int vz = 4 * WSZ * 4 + 16 * hi;                // shared zero row (broadcast)

    f32x16 acc0 = {}, acc1a = {}, acc1b = {};

    #pragma unroll 2
    for (int r = 0; r < 32; ++r) {
        const int va = (n >= r) ? (va2 - 2560) : vz;     // A row (n-r) or zeros
        const uint4 a00 = *(const uint4*)(ldsb + va);          // A(-r,  s0)
        const uint4 a01 = *(const uint4*)(ldsb + va + 32);     // A(-r,  s1)
        const uint4 a10 = *(const uint4*)(ldsb + va2);         // A(32-r,s0)
        const uint4 a11 = *(const uint4*)(ldsb + va2 + 32);    // A(32-r,s1)

        uint2 q0, q1, q2;
        uint4 B;
        // B00 = T_r, s0
        q0 = *(const uint2*)(ldsb + vk + 2048);
        q1 = *(const uint2*)(ldsb + vk + 2056);
        q2 = *(const uint2*)(ldsb + vk + 2064);
        SEL4(q0.x, q0.y, q1.x, q1.y, q2.x, q2.y, B);
        acc0  = MFMA(a00, B, acc0);
        acc1a = MFMA(a10, B, acc1a);
        // B01 = T_r, s1
        q0 = *(const uint2*)(ldsb + vk + 2080);
        q1 = *(const uint2*)(ldsb + vk + 2088);
        q2 = *(const uint2*)(ldsb + vk + 2096);
        SEL4(q0.x, q0.y, q1.x, q1.y, q2.x, q2.y, B);
        acc0  = MFMA(a01, B, acc0);
        acc1a = MFMA(a11, B, acc1a);
        // B10 = T_{r+32}, s0
        q0 = *(const uint2*)(ldsb + vk);
        q1 = *(const uint2*)(ldsb + vk + 8);
        q2 = *(const uint2*)(ldsb + vk + 16);
        SEL4(q0.x, q0.y, q1.x, q1.y, q2.x, q2.y, B);
        acc1b = MFMA(a00, B, acc1b);
        // B11 = T_{r+32}, s1
        q0 = *(const uint2*)(ldsb + vk + 32);
        q1 = *(const uint2*)(ldsb + vk + 40);
        q2 = *(const uint2*)(ldsb + vk + 48);
        SEL4(q0.x, q0.y, q1.x, q1.y, q2.x, q2.y, B);
        acc1b = MFMA(a01, B, acc1b);

        va2 -= 80;      // next shift: row index -1
        vk  -= 64;      // next shift: -32 krev elements = -16 u32
    }

    // ---- epilogue: y[32p + n] = acc + x + bias ----
    const float bv = bias[row & 2047];
    #pragma unroll
    for (int mt = 0; mt < 2; ++mt) {
        #pragma unroll
        for (int t = 0; t < 16; ++t) {
            const int rloc = (t & 3) + 8 * (t >> 2) + 4 * hi;  // verified 32x32 C/D row map
            const int p = mt * 32 + rloc;
            const uint w = xw[p * XPITCH + (n >> 1)];
            const float xr = __uint_as_float((n & 1) ? (w & 0xffff0000u) : (w << 16));
            const float a = mt ? (acc1a[t] + acc1b[t]) : acc0[t];
            out[rb + (size_t)p * 32 + n] = a + xr + bv;
        }
    }
}

extern "C" void kernel_launch(void* const* d_in, const int* in_sizes, int n_in,
                              void* d_out, int out_size, void* d_ws, size_t ws_size,
                              hipStream_t stream) {
    const float* x    = (const float*)d_in[0];   // (4, 2048, 2048) f32
    const float* kern = (const float*)d_in[1];   // (4, 2048, 2048) f32
    const float* bias = (const float*)d_in[2];   // (2048,) f32
    float* out = (float*)d_out;                  // (4, 2048, 2048) f32

    hipLaunchKernelGGL(hyena_mfma, dim3(2048), dim3(256), 0, stream,
                       x, kern, bias, out);
}